// Round 1
// 146.810 us; speedup vs baseline: 1.0100x; 1.0100x over previous
//
#include <hip/hip_runtime.h>
#include <math.h>

#define NODE_D 128
#define HID 16

#if __has_builtin(__builtin_amdgcn_cvt_pk_f32_fp8) && __has_builtin(__builtin_amdgcn_cvt_pk_fp8_f32)
#define USE_FP8 1
#define RECB 192   // [z fp8 128B][U f16 32B][V f16 32B] -> 3 cache lines
#define UOFF 128
#define VOFF 160
#else
#define USE_FP8 0
#define RECB 320   // [z f16 256B][U f16 32B][V f16 32B] -> 5 cache lines
#define UOFF 256
#define VOFF 288
#endif

typedef _Float16 f16x8_t __attribute__((ext_vector_type(8)));
typedef _Float16 f16x2_t __attribute__((ext_vector_type(2)));
typedef float    f32x4_t __attribute__((ext_vector_type(4)));
typedef float    f32x2_t __attribute__((ext_vector_type(2)));

// ---------------------------------------------------------------------------
// Kernel 1 (MFMA f16): builds node records.
//   rec[n] = { z[n] (fp8 or f16) , U[n]=f16(z@W1[:128]+b1) , V[n]=f16(z@W1[128:]) }
// W1 staged once per block into LDS in fragment order; one wave = 16 nodes.
// A layout: A[m=lane&15][k=quad*8+j (+32s)]; C/D: col=lane&15, row=quad*4+reg.
// ---------------------------------------------------------------------------
__global__ __launch_bounds__(256) void precompute_mfma(
    const float* __restrict__ z, const float* __restrict__ W1,
    const float* __restrict__ b1,
    unsigned char* __restrict__ rec, int n_nodes)
{
    __shared__ _Float16 ldsU[4096];   // 8 KB, fragment-ordered W1 rows 0..127
    __shared__ _Float16 ldsV[4096];   // 8 KB, rows 128..255

    const int tid = threadIdx.x;
    #pragma unroll
    for (int i = 0; i < 32; ++i) {
        const int e = i * 256 + tid;          // coalesced over W1's 8192 floats
        const float val = W1[e];
        int k = e >> 4;
        const int m = e & 15;
        _Float16* dst = ldsU;
        if (k >= NODE_D) { k -= NODE_D; dst = ldsV; }
        const int s = k >> 5, q = (k >> 3) & 3, jj = k & 7;
        dst[(((s * 4 + q) * 16 + m) << 3) + jj] = (_Float16)val;
    }
    __syncthreads();

    const int wave  = tid >> 6;
    const int lane  = tid & 63;
    const int m     = lane & 15;
    const int quad  = lane >> 4;
    const int nbase = blockIdx.x * 64 + wave * 16;
    const int node  = nbase + m;
    const int nodec = node < n_nodes ? node : (n_nodes - 1);

    // ---- A fragments from z (+ write compressed z into the record) ----
    f16x8_t a[4];
    const float4* zrow = (const float4*)(z + (size_t)nodec * NODE_D);
    unsigned char* myrec = rec + (size_t)node * RECB;
    #pragma unroll
    for (int s = 0; s < 4; ++s) {
        float4 f0 = zrow[s * 8 + quad * 2];
        float4 f1 = zrow[s * 8 + quad * 2 + 1];
        union { f16x8_t v; _Float16 h[8]; uint4 q4; } ta;
        ta.h[0] = (_Float16)f0.x; ta.h[1] = (_Float16)f0.y;
        ta.h[2] = (_Float16)f0.z; ta.h[3] = (_Float16)f0.w;
        ta.h[4] = (_Float16)f1.x; ta.h[5] = (_Float16)f1.y;
        ta.h[6] = (_Float16)f1.z; ta.h[7] = (_Float16)f1.w;
        a[s] = ta.v;
        if (node < n_nodes) {
#if USE_FP8
            // pack 8 floats -> 8 fp8 e4m3 (RNE), dims s*32+quad*8 .. +7
            int w0 = __builtin_amdgcn_cvt_pk_fp8_f32(f0.x, f0.y, 0, false);
            w0     = __builtin_amdgcn_cvt_pk_fp8_f32(f0.z, f0.w, w0, true);
            int w1 = __builtin_amdgcn_cvt_pk_fp8_f32(f1.x, f1.y, 0, false);
            w1     = __builtin_amdgcn_cvt_pk_fp8_f32(f1.z, f1.w, w1, true);
            *(uint2*)(myrec + ((s * 4 + quad) << 3)) = make_uint2((unsigned)w0, (unsigned)w1);
#else
            *(uint4*)(myrec + ((s * 4 + quad) << 4)) = ta.q4;
#endif
        }
    }

    // ---- B fragments from LDS, MFMA (b1 folded into U accumulator) ----
    const float bias = b1[m];
    f32x4_t accU = {bias, bias, bias, bias};
    f32x4_t accV = {0.f, 0.f, 0.f, 0.f};
    #pragma unroll
    for (int s = 0; s < 4; ++s) {
        f16x8_t bu = *(const f16x8_t*)(ldsU + (((s * 4 + quad) * 16 + m) << 3));
        f16x8_t bv = *(const f16x8_t*)(ldsV + (((s * 4 + quad) * 16 + m) << 3));
        accU = __builtin_amdgcn_mfma_f32_16x16x32_f16(a[s], bu, accU, 0, 0, 0);
        accV = __builtin_amdgcn_mfma_f32_16x16x32_f16(a[s], bv, accV, 0, 0, 0);
    }

    // ---- store U/V f16 into the record ----
    #pragma unroll
    for (int r = 0; r < 4; ++r) {
        const int nodeo = nbase + quad * 4 + r;
        if (nodeo < n_nodes) {
            unsigned char* orec = rec + (size_t)nodeo * RECB;
            *(_Float16*)(orec + UOFF + 2 * m) = (_Float16)accU[r];
            *(_Float16*)(orec + VOFF + 2 * m) = (_Float16)accV[r];
        }
    }
}

__device__ __forceinline__ float softplus_f(float x) {
    return fmaxf(x, 0.f) + log1pf(expf(-fabsf(x)));
}

#if USE_FP8

// dot of 16 fp8 pairs (one uint4 each side), packed-f32 accumulation.
// 16 cvt_pk + 8 v_pk_fma_f32 instead of 16 cvt + 16 scalar fma.
__device__ __forceinline__ f32x2_t dot2_fp8x16(uint4 a, uint4 c, f32x2_t acc) {
    const unsigned* au = (const unsigned*)&a;
    const unsigned* cu = (const unsigned*)&c;
    #pragma unroll
    for (int q = 0; q < 4; ++q) {
        f32x2_t alo = __builtin_amdgcn_cvt_pk_f32_fp8(au[q], false);
        f32x2_t clo = __builtin_amdgcn_cvt_pk_f32_fp8(cu[q], false);
        acc += alo * clo;                       // v_pk_fma_f32
        f32x2_t ahi = __builtin_amdgcn_cvt_pk_f32_fp8(au[q], true);
        f32x2_t chi = __builtin_amdgcn_cvt_pk_f32_fp8(cu[q], true);
        acc += ahi * chi;
    }
    return acc;
}

__device__ __forceinline__ f16x2_t relu2h(f16x2_t x) {
    const f16x2_t z = {(_Float16)0.f, (_Float16)0.f};
#if __has_builtin(__builtin_elementwise_max)
    return __builtin_elementwise_max(x, z);     // v_pk_max_f16
#else
    f16x2_t r;
    r.x = x.x > z.x ? x.x : z.x;
    r.y = x.y > z.y ? x.y : z.y;
    return r;
#endif
}

// relu(u+v) . w2h  for one edge's two hidden units (packed f16 ops + fdot2)
__device__ __forceinline__ float head2(f16x2_t u, f16x2_t v, f16x2_t w2h) {
    f16x2_t r = relu2h(u + v);                  // v_pk_add_f16 + v_pk_max_f16
#if __has_builtin(__builtin_amdgcn_fdot2)
    return __builtin_amdgcn_fdot2(r, w2h, 0.f, false);  // v_dot2_f32_f16
#else
    return (float)r.x * (float)w2h.x + (float)r.y * (float)w2h.y;
#endif
}

// ---------------------------------------------------------------------------
// Kernel 2 (fp8 records): 8 lanes per edge, 4 edges per group.
// Per thread: 8 z uint4 gathers (16 B/lane covers the 128 B fp8 z block)
// + 8 f16x2 U/V loads in flight. 3-stage reduction.
// ---------------------------------------------------------------------------
__global__ __launch_bounds__(256) void edge_kernel_rec(
    const unsigned char* __restrict__ rec, const int* __restrict__ ei,
    const float* __restrict__ W2, const float* __restrict__ b2,
    float* __restrict__ out, int E)
{
    const int gid  = blockIdx.x * 256 + threadIdx.x;
    const int g    = gid >> 3;          // edge-quad id
    const int lane = threadIdx.x & 7;
    const int e0   = 4 * g;
    if (e0 >= E) return;
    const bool full = (e0 + 3) < E;

    int4 rr, cc;
    if (full) {
        rr = *(const int4*)(ei + e0);
        cc = *(const int4*)(ei + E + e0);
    } else {
        const int i1 = min(e0 + 1, E - 1), i2 = min(e0 + 2, E - 1), i3 = min(e0 + 3, E - 1);
        rr = make_int4(ei[e0], ei[i1], ei[i2], ei[i3]);
        cc = make_int4(ei[E + e0], ei[E + i1], ei[E + i2], ei[E + i3]);
    }

    const unsigned char* R0 = rec + (size_t)rr.x * RECB;
    const unsigned char* R1 = rec + (size_t)rr.y * RECB;
    const unsigned char* R2 = rec + (size_t)rr.z * RECB;
    const unsigned char* R3 = rec + (size_t)rr.w * RECB;
    const unsigned char* C0 = rec + (size_t)cc.x * RECB;
    const unsigned char* C1 = rec + (size_t)cc.y * RECB;
    const unsigned char* C2 = rec + (size_t)cc.z * RECB;
    const unsigned char* C3 = rec + (size_t)cc.w * RECB;

    const int zo = lane << 4;     // 16 B per lane within the 128 B fp8 z block
    uint4 za0 = *(const uint4*)(R0 + zo);
    uint4 zc0 = *(const uint4*)(C0 + zo);
    uint4 za1 = *(const uint4*)(R1 + zo);
    uint4 zc1 = *(const uint4*)(C1 + zo);
    uint4 za2 = *(const uint4*)(R2 + zo);
    uint4 zc2 = *(const uint4*)(C2 + zo);
    uint4 za3 = *(const uint4*)(R3 + zo);
    uint4 zc3 = *(const uint4*)(C3 + zo);

    const int uo = UOFF + (lane << 2);   // lane handles hidden units 2l, 2l+1
    const int vo = VOFF + (lane << 2);
    f16x2_t u0 = *(const f16x2_t*)(R0 + uo);
    f16x2_t v0 = *(const f16x2_t*)(C0 + vo);
    f16x2_t u1 = *(const f16x2_t*)(R1 + uo);
    f16x2_t v1 = *(const f16x2_t*)(C1 + vo);
    f16x2_t u2 = *(const f16x2_t*)(R2 + uo);
    f16x2_t v2 = *(const f16x2_t*)(C2 + vo);
    f16x2_t u3 = *(const f16x2_t*)(R3 + uo);
    f16x2_t v3 = *(const f16x2_t*)(C3 + vo);
    const float2 w2 = ((const float2*)W2)[lane];
    const f16x2_t w2h = {(_Float16)w2.x, (_Float16)w2.y};

    const f32x2_t zero2 = {0.f, 0.f};
    f32x2_t q0 = dot2_fp8x16(za0, zc0, zero2);
    f32x2_t q1 = dot2_fp8x16(za1, zc1, zero2);
    f32x2_t q2 = dot2_fp8x16(za2, zc2, zero2);
    f32x2_t q3 = dot2_fp8x16(za3, zc3, zero2);
    float p0 = q0.x + q0.y;
    float p1 = q1.x + q1.y;
    float p2 = q2.x + q2.y;
    float p3 = q3.x + q3.y;

    float t0 = head2(u0, v0, w2h);
    float t1 = head2(u1, v1, w2h);
    float t2 = head2(u2, v2, w2h);
    float t3 = head2(u3, v3, w2h);

    #pragma unroll
    for (int s = 1; s < 8; s <<= 1) {
        p0 += __shfl_xor(p0, s);
        p1 += __shfl_xor(p1, s);
        p2 += __shfl_xor(p2, s);
        p3 += __shfl_xor(p3, s);
        t0 += __shfl_xor(t0, s);
        t1 += __shfl_xor(t1, s);
        t2 += __shfl_xor(t2, s);
        t3 += __shfl_xor(t3, s);
    }

    if (lane == 0) {
        const float bb = b2[0];
        float w0 = softplus_f(t0 + bb);
        float w1 = softplus_f(t1 + bb);
        float ws = softplus_f(t2 + bb);
        float w3 = softplus_f(t3 + bb);
        if (full) {   // e0 % 4 == 0 and E % 4 == 0 -> 16 B aligned
            *(float4*)(out + e0)     = make_float4(p0, p1, p2, p3);
            *(float4*)(out + E + e0) = make_float4(w0, w1, ws, w3);
        } else {
            const float pv[4] = {p0, p1, p2, p3};
            const float wv[4] = {w0, w1, ws, w3};
            for (int j = 0; j < 4 && e0 + j < E; ++j) {
                out[e0 + j]     = pv[j];
                out[E + e0 + j] = wv[j];
            }
        }
    }
}

#else  // !USE_FP8 — f16 records, 16 lanes per edge, 4 edges per group (R6 path)

__device__ __forceinline__ float dot_f16x8(uint4 a, uint4 c) {
    union { uint4 u; f16x2_t h[4]; } A, C;
    A.u = a; C.u = c;
    float p = 0.f;
#if __has_builtin(__builtin_amdgcn_fdot2)
    #pragma unroll
    for (int q = 0; q < 4; ++q)
        p = __builtin_amdgcn_fdot2(A.h[q], C.h[q], p, false);
#else
    #pragma unroll
    for (int q = 0; q < 4; ++q) {
        p = fmaf((float)A.h[q][0], (float)C.h[q][0], p);
        p = fmaf((float)A.h[q][1], (float)C.h[q][1], p);
    }
#endif
    return p;
}

__global__ __launch_bounds__(256) void edge_kernel_rec(
    const unsigned char* __restrict__ rec, const int* __restrict__ ei,
    const float* __restrict__ W2, const float* __restrict__ b2,
    float* __restrict__ out, int E)
{
    const int gid  = blockIdx.x * 256 + threadIdx.x;
    const int g    = gid >> 4;
    const int lane = threadIdx.x & 15;
    const int e0   = 4 * g;
    if (e0 >= E) return;
    const bool full = (e0 + 3) < E;

    int4 rr, cc;
    if (full) {
        rr = *(const int4*)(ei + e0);
        cc = *(const int4*)(ei + E + e0);
    } else {
        const int i1 = min(e0 + 1, E - 1), i2 = min(e0 + 2, E - 1), i3 = min(e0 + 3, E - 1);
        rr = make_int4(ei[e0], ei[i1], ei[i2], ei[i3]);
        cc = make_int4(ei[E + e0], ei[E + i1], ei[E + i2], ei[E + i3]);
    }

    const unsigned char* R0 = rec + (size_t)rr.x * RECB;
    const unsigned char* R1 = rec + (size_t)rr.y * RECB;
    const unsigned char* R2 = rec + (size_t)rr.z * RECB;
    const unsigned char* R3 = rec + (size_t)rr.w * RECB;
    const unsigned char* C0 = rec + (size_t)cc.x * RECB;
    const unsigned char* C1 = rec + (size_t)cc.y * RECB;
    const unsigned char* C2 = rec + (size_t)cc.z * RECB;
    const unsigned char* C3 = rec + (size_t)cc.w * RECB;

    const int zo = lane << 4;
    uint4 za0 = *(const uint4*)(R0 + zo);
    uint4 zc0 = *(const uint4*)(C0 + zo);
    uint4 za1 = *(const uint4*)(R1 + zo);
    uint4 zc1 = *(const uint4*)(C1 + zo);
    uint4 za2 = *(const uint4*)(R2 + zo);
    uint4 zc2 = *(const uint4*)(C2 + zo);
    uint4 za3 = *(const uint4*)(R3 + zo);
    uint4 zc3 = *(const uint4*)(C3 + zo);

    const int uo = UOFF + 2 * lane;
    const int vo = VOFF + 2 * lane;
    float u0 = (float)*(const _Float16*)(R0 + uo);
    float v0 = (float)*(const _Float16*)(C0 + vo);
    float u1 = (float)*(const _Float16*)(R1 + uo);
    float v1 = (float)*(const _Float16*)(C1 + vo);
    float u2 = (float)*(const _Float16*)(R2 + uo);
    float v2 = (float)*(const _Float16*)(C2 + vo);
    float u3 = (float)*(const _Float16*)(R3 + uo);
    float v3 = (float)*(const _Float16*)(C3 + vo);
    float w2 = W2[lane];

    float p0 = dot_f16x8(za0, zc0);
    float p1 = dot_f16x8(za1, zc1);
    float p2 = dot_f16x8(za2, zc2);
    float p3 = dot_f16x8(za3, zc3);
    #pragma unroll
    for (int s = 1; s < 16; s <<= 1) {
        p0 += __shfl_xor(p0, s);
        p1 += __shfl_xor(p1, s);
        p2 += __shfl_xor(p2, s);
        p3 += __shfl_xor(p3, s);
    }

    float t0 = fmaxf(u0 + v0, 0.f) * w2;
    float t1 = fmaxf(u1 + v1, 0.f) * w2;
    float t2 = fmaxf(u2 + v2, 0.f) * w2;
    float t3 = fmaxf(u3 + v3, 0.f) * w2;
    #pragma unroll
    for (int s = 1; s < 16; s <<= 1) {
        t0 += __shfl_xor(t0, s);
        t1 += __shfl_xor(t1, s);
        t2 += __shfl_xor(t2, s);
        t3 += __shfl_xor(t3, s);
    }

    if (lane == 0) {
        const float bb = b2[0];
        float w0 = softplus_f(t0 + bb);
        float w1 = softplus_f(t1 + bb);
        float ws = softplus_f(t2 + bb);
        float w3 = softplus_f(t3 + bb);
        if (full) {
            *(float4*)(out + e0)     = make_float4(p0, p1, p2, p3);
            *(float4*)(out + E + e0) = make_float4(w0, w1, ws, w3);
        } else {
            const float pv[4] = {p0, p1, p2, p3};
            const float wv[4] = {w0, w1, ws, w3};
            for (int j = 0; j < 4 && e0 + j < E; ++j) {
                out[e0 + j]     = pv[j];
                out[E + e0 + j] = wv[j];
            }
        }
    }
}
#endif  // USE_FP8

// ---------------------------------------------------------------------------
// Fallbacks (only if d_ws can't hold the record array)
// ---------------------------------------------------------------------------
__global__ __launch_bounds__(256) void precompute_scalar(
    const float* __restrict__ z, const float* __restrict__ W1,
    const float* __restrict__ b1,
    float* __restrict__ U, float* __restrict__ V, int n_nodes)
{
    const int node = blockIdx.x * 256 + threadIdx.x;
    if (node >= n_nodes) return;
    const float4* zp = (const float4*)(z + (size_t)node * NODE_D);
    float u[HID], v[HID];
    #pragma unroll
    for (int j = 0; j < HID; ++j) { u[j] = b1[j]; v[j] = 0.f; }
    #pragma unroll 1
    for (int c = 0; c < NODE_D / 4; ++c) {
        float4 za = zp[c];
        const float* wu = W1 + (size_t)c * 4 * HID;
        const float* wv = wu + NODE_D * HID;
        #pragma unroll
        for (int j = 0; j < HID; ++j) {
            u[j] = fmaf(za.x, wu[j], fmaf(za.y, wu[HID + j],
                   fmaf(za.z, wu[2 * HID + j], fmaf(za.w, wu[3 * HID + j], u[j]))));
            v[j] = fmaf(za.x, wv[j], fmaf(za.y, wv[HID + j],
                   fmaf(za.z, wv[2 * HID + j], fmaf(za.w, wv[3 * HID + j], v[j]))));
        }
    }
    float4* up = (float4*)(U + (size_t)node * HID);
    float4* vp = (float4*)(V + (size_t)node * HID);
    #pragma unroll
    for (int q = 0; q < 4; ++q) {
        up[q] = make_float4(u[4*q], u[4*q+1], u[4*q+2], u[4*q+3]);
        vp[q] = make_float4(v[4*q], v[4*q+1], v[4*q+2], v[4*q+3]);
    }
}

__global__ __launch_bounds__(256) void edge_kernel_f32(
    const float* __restrict__ z, const int* __restrict__ ei,
    const float* __restrict__ U, const float* __restrict__ V,
    const float* __restrict__ W2, const float* __restrict__ b2,
    float* __restrict__ out, int E)
{
    const int gid  = blockIdx.x * blockDim.x + threadIdx.x;
    const int eid  = gid >> 4;
    const int lane = threadIdx.x & 15;
    if (eid >= E) return;
    const int row = ei[eid];
    const int col = ei[E + eid];
    const float4* zr = (const float4*)(z + (size_t)row * NODE_D);
    const float4* zc = (const float4*)(z + (size_t)col * NODE_D);
    float4 a0 = zr[lane], a1 = zr[lane + 16];
    float4 c0 = zc[lane], c1 = zc[lane + 16];
    float p = a0.x*c0.x + a0.y*c0.y + a0.z*c0.z + a0.w*c0.w
            + a1.x*c1.x + a1.y*c1.y + a1.z*c1.z + a1.w*c1.w;
    p += __shfl_xor(p, 1); p += __shfl_xor(p, 2);
    p += __shfl_xor(p, 4); p += __shfl_xor(p, 8);
    float t = fmaxf(U[(size_t)row * HID + lane] + V[(size_t)col * HID + lane], 0.f) * W2[lane];
    t += __shfl_xor(t, 1); t += __shfl_xor(t, 2);
    t += __shfl_xor(t, 4); t += __shfl_xor(t, 8);
    if (lane == 0) {
        float x = t + b2[0];
        out[eid]     = p;
        out[E + eid] = softplus_f(x);
    }
}

extern "C" void kernel_launch(void* const* d_in, const int* in_sizes, int n_in,
                              void* d_out, int out_size, void* d_ws, size_t ws_size,
                              hipStream_t stream) {
    const float* z  = (const float*)d_in[0];
    const int*   ei = (const int*)  d_in[1];
    const float* W1 = (const float*)d_in[2];
    const float* b1 = (const float*)d_in[3];
    const float* W2 = (const float*)d_in[4];
    const float* b2 = (const float*)d_in[5];
    float* out = (float*)d_out;

    const int n_nodes = in_sizes[0] / NODE_D;   // 100000
    const int E       = in_sizes[1] / 2;        // 600000

    const size_t needRec = (size_t)n_nodes * RECB;   // 19.2 MB (fp8) / 32 MB (f16)
    const int use_rec    = (ws_size >= needRec);

    if (use_rec) {
        unsigned char* rec = (unsigned char*)d_ws;
        precompute_mfma<<<(n_nodes + 63) / 64, 256, 0, stream>>>(
            z, W1, b1, rec, n_nodes);
        const long long groups  = ((long long)E + 3) / 4;
#if USE_FP8
        const long long threads = groups * 8;
#else
        const long long threads = groups * 16;
#endif
        edge_kernel_rec<<<(unsigned)((threads + 255) / 256), 256, 0, stream>>>(
            rec, ei, W2, b2, out, E);
    } else {
        float* U = (float*)d_ws;
        float* V = U + (size_t)n_nodes * HID;
        precompute_scalar<<<(n_nodes + 255) / 256, 256, 0, stream>>>(
            z, W1, b1, U, V, n_nodes);
        const long long threads = (long long)E * 16;
        edge_kernel_f32<<<(unsigned)((threads + 255) / 256), 256, 0, stream>>>(
            z, ei, U, V, W2, b2, out, E);
    }
}

// Round 5
// 146.773 us; speedup vs baseline: 1.0103x; 1.0003x over previous
//
#include <hip/hip_runtime.h>
#include <math.h>

#define NODE_D 128
#define HID 16

#if __has_builtin(__builtin_amdgcn_cvt_pk_f32_fp8) && __has_builtin(__builtin_amdgcn_cvt_pk_fp8_f32)
#define USE_FP8 1
#define RECB 192   // [z fp8 128B][U f16 32B][V f16 32B] -> 3 cache lines
#define UOFF 128
#define VOFF 160
#else
#define USE_FP8 0
#define RECB 320   // [z f16 256B][U f16 32B][V f16 32B] -> 5 cache lines
#define UOFF 256
#define VOFF 288
#endif

typedef _Float16 f16x8_t __attribute__((ext_vector_type(8)));
typedef _Float16 f16x2_t __attribute__((ext_vector_type(2)));
typedef float    f32x4_t __attribute__((ext_vector_type(4)));
typedef float    f32x2_t __attribute__((ext_vector_type(2)));
typedef int      i32x4_t __attribute__((ext_vector_type(4)));

// ---------------------------------------------------------------------------
// Kernel 1 (MFMA f16): builds node records.
//   rec[n] = { z[n] (fp8 or f16) , U[n]=f16(z@W1[:128]+b1) , V[n]=f16(z@W1[128:]) }
// W1 is [256][16] = 4096 floats, staged once per block into LDS in fragment
// order (i < 16 stages exactly 4096 — in-bounds; earlier i<32 was OOB UB).
// A layout: A[m=lane&15][k=quad*8+j (+32s)]; C/D: col=lane&15, row=quad*4+reg.
// ---------------------------------------------------------------------------
__global__ __launch_bounds__(256) void precompute_mfma(
    const float* __restrict__ z, const float* __restrict__ W1,
    const float* __restrict__ b1,
    unsigned char* __restrict__ rec, int n_nodes)
{
    __shared__ _Float16 ldsU[2048];   // 4 KB, fragment-ordered W1 rows 0..127
    __shared__ _Float16 ldsV[2048];   // 4 KB, rows 128..255

    const int tid = threadIdx.x;
    #pragma unroll
    for (int i = 0; i < 16; ++i) {
        const int e = i * 256 + tid;          // coalesced over W1's 4096 floats
        const float val = W1[e];
        int k = e >> 4;                        // W1 row (0..255)
        const int m = e & 15;                  // W1 col (hidden unit)
        _Float16* dst = ldsU;
        if (k >= NODE_D) { k -= NODE_D; dst = ldsV; }
        const int s = k >> 5, q = (k >> 3) & 3, jj = k & 7;
        dst[(((s * 4 + q) * 16 + m) << 3) + jj] = (_Float16)val;   // max 2047
    }
    __syncthreads();

    const int wave  = tid >> 6;
    const int lane  = tid & 63;
    const int m     = lane & 15;
    const int quad  = lane >> 4;
    const int nbase = blockIdx.x * 64 + wave * 16;
    const int node  = nbase + m;
    const int nodec = node < n_nodes ? node : (n_nodes - 1);

    // ---- A fragments from z (+ write compressed z into the record) ----
    // z is streamed once -> non-temporal loads (keep L2 for the record array).
    f16x8_t a[4];
    const f32x4_t* zrow = (const f32x4_t*)(z + (size_t)nodec * NODE_D);
    unsigned char* myrec = rec + (size_t)node * RECB;
    #pragma unroll
    for (int s = 0; s < 4; ++s) {
        f32x4_t f0 = __builtin_nontemporal_load(zrow + s * 8 + quad * 2);
        f32x4_t f1 = __builtin_nontemporal_load(zrow + s * 8 + quad * 2 + 1);
        union { f16x8_t v; _Float16 h[8]; uint4 q4; } ta;
        ta.h[0] = (_Float16)f0.x; ta.h[1] = (_Float16)f0.y;
        ta.h[2] = (_Float16)f0.z; ta.h[3] = (_Float16)f0.w;
        ta.h[4] = (_Float16)f1.x; ta.h[5] = (_Float16)f1.y;
        ta.h[6] = (_Float16)f1.z; ta.h[7] = (_Float16)f1.w;
        a[s] = ta.v;
        if (node < n_nodes) {
#if USE_FP8
            // pack 8 floats -> 8 fp8 e4m3 (RNE), dims s*32+quad*8 .. +7
            int w0 = __builtin_amdgcn_cvt_pk_fp8_f32(f0.x, f0.y, 0, false);
            w0     = __builtin_amdgcn_cvt_pk_fp8_f32(f0.z, f0.w, w0, true);
            int w1 = __builtin_amdgcn_cvt_pk_fp8_f32(f1.x, f1.y, 0, false);
            w1     = __builtin_amdgcn_cvt_pk_fp8_f32(f1.z, f1.w, w1, true);
            *(uint2*)(myrec + ((s * 4 + quad) << 3)) = make_uint2((unsigned)w0, (unsigned)w1);
#else
            *(uint4*)(myrec + ((s * 4 + quad) << 4)) = ta.q4;
#endif
        }
    }

    // ---- B fragments from LDS, MFMA (b1 folded into U accumulator) ----
    const float bias = b1[m];
    f32x4_t accU = {bias, bias, bias, bias};
    f32x4_t accV = {0.f, 0.f, 0.f, 0.f};
    #pragma unroll
    for (int s = 0; s < 4; ++s) {
        f16x8_t bu = *(const f16x8_t*)(ldsU + (((s * 4 + quad) * 16 + m) << 3));
        f16x8_t bv = *(const f16x8_t*)(ldsV + (((s * 4 + quad) * 16 + m) << 3));
        accU = __builtin_amdgcn_mfma_f32_16x16x32_f16(a[s], bu, accU, 0, 0, 0);
        accV = __builtin_amdgcn_mfma_f32_16x16x32_f16(a[s], bv, accV, 0, 0, 0);
    }

    // ---- store U/V f16 into the record ----
    #pragma unroll
    for (int r = 0; r < 4; ++r) {
        const int nodeo = nbase + quad * 4 + r;
        if (nodeo < n_nodes) {
            unsigned char* orec = rec + (size_t)nodeo * RECB;
            *(_Float16*)(orec + UOFF + 2 * m) = (_Float16)accU[r];
            *(_Float16*)(orec + VOFF + 2 * m) = (_Float16)accV[r];
        }
    }
}

__device__ __forceinline__ float softplus_f(float x) {
    return fmaxf(x, 0.f) + log1pf(expf(-fabsf(x)));
}

#if USE_FP8

// dot of 16 fp8 pairs (one uint4 each side), packed-f32 accumulation.
// 16 cvt_pk + 8 v_pk_fma_f32.
__device__ __forceinline__ f32x2_t dot2_fp8x16(uint4 a, uint4 c, f32x2_t acc) {
    const unsigned* au = (const unsigned*)&a;
    const unsigned* cu = (const unsigned*)&c;
    #pragma unroll
    for (int q = 0; q < 4; ++q) {
        f32x2_t alo = __builtin_amdgcn_cvt_pk_f32_fp8(au[q], false);
        f32x2_t clo = __builtin_amdgcn_cvt_pk_f32_fp8(cu[q], false);
        acc += alo * clo;                       // v_pk_fma_f32
        f32x2_t ahi = __builtin_amdgcn_cvt_pk_f32_fp8(au[q], true);
        f32x2_t chi = __builtin_amdgcn_cvt_pk_f32_fp8(cu[q], true);
        acc += ahi * chi;
    }
    return acc;
}

__device__ __forceinline__ f16x2_t relu2h(f16x2_t x) {
    const f16x2_t z = {(_Float16)0.f, (_Float16)0.f};
#if __has_builtin(__builtin_elementwise_max)
    return __builtin_elementwise_max(x, z);     // v_pk_max_f16
#else
    f16x2_t r;
    r.x = x.x > z.x ? x.x : z.x;
    r.y = x.y > z.y ? x.y : z.y;
    return r;
#endif
}

// relu(u+v) . w2h  for one edge's two hidden units (packed f16 ops + fdot2)
__device__ __forceinline__ float head2(f16x2_t u, f16x2_t v, f16x2_t w2h) {
    f16x2_t r = relu2h(u + v);                  // v_pk_add_f16 + v_pk_max_f16
#if __has_builtin(__builtin_amdgcn_fdot2)
    return __builtin_amdgcn_fdot2(r, w2h, 0.f, false);  // v_dot2_f32_f16
#else
    return (float)r.x * (float)w2h.x + (float)r.y * (float)w2h.y;
#endif
}

// ---------------------------------------------------------------------------
// Kernel 2 (fp8 records): 8 lanes per edge, 4 edges per group.
// Per thread: 8 z uint4 gathers (16 B/lane covers the 128 B fp8 z block)
// + 8 f16x2 U/V loads in flight. 3-stage reduction.
// ei loads and out stores are non-temporal (streamed once; keep L2 for rec).
// ---------------------------------------------------------------------------
__global__ __launch_bounds__(256) void edge_kernel_rec(
    const unsigned char* __restrict__ rec, const int* __restrict__ ei,
    const float* __restrict__ W2, const float* __restrict__ b2,
    float* __restrict__ out, int E)
{
    const int gid  = blockIdx.x * 256 + threadIdx.x;
    const int g    = gid >> 3;          // edge-quad id
    const int lane = threadIdx.x & 7;
    const int e0   = 4 * g;
    if (e0 >= E) return;
    const bool full = (e0 + 3) < E;

    i32x4_t rr, cc;
    if (full) {
        rr = __builtin_nontemporal_load((const i32x4_t*)(ei + e0));
        cc = __builtin_nontemporal_load((const i32x4_t*)(ei + E + e0));
    } else {
        const int i1 = min(e0 + 1, E - 1), i2 = min(e0 + 2, E - 1), i3 = min(e0 + 3, E - 1);
        rr = (i32x4_t){ei[e0], ei[i1], ei[i2], ei[i3]};
        cc = (i32x4_t){ei[E + e0], ei[E + i1], ei[E + i2], ei[E + i3]};
    }

    const unsigned char* R0 = rec + (size_t)rr.x * RECB;
    const unsigned char* R1 = rec + (size_t)rr.y * RECB;
    const unsigned char* R2 = rec + (size_t)rr.z * RECB;
    const unsigned char* R3 = rec + (size_t)rr.w * RECB;
    const unsigned char* C0 = rec + (size_t)cc.x * RECB;
    const unsigned char* C1 = rec + (size_t)cc.y * RECB;
    const unsigned char* C2 = rec + (size_t)cc.z * RECB;
    const unsigned char* C3 = rec + (size_t)cc.w * RECB;

    const int zo = lane << 4;     // 16 B per lane within the 128 B fp8 z block
    uint4 za0 = *(const uint4*)(R0 + zo);
    uint4 zc0 = *(const uint4*)(C0 + zo);
    uint4 za1 = *(const uint4*)(R1 + zo);
    uint4 zc1 = *(const uint4*)(C1 + zo);
    uint4 za2 = *(const uint4*)(R2 + zo);
    uint4 zc2 = *(const uint4*)(C2 + zo);
    uint4 za3 = *(const uint4*)(R3 + zo);
    uint4 zc3 = *(const uint4*)(C3 + zo);

    const int uo = UOFF + (lane << 2);   // lane handles hidden units 2l, 2l+1
    const int vo = VOFF + (lane << 2);
    f16x2_t u0 = *(const f16x2_t*)(R0 + uo);
    f16x2_t v0 = *(const f16x2_t*)(C0 + vo);
    f16x2_t u1 = *(const f16x2_t*)(R1 + uo);
    f16x2_t v1 = *(const f16x2_t*)(C1 + vo);
    f16x2_t u2 = *(const f16x2_t*)(R2 + uo);
    f16x2_t v2 = *(const f16x2_t*)(C2 + vo);
    f16x2_t u3 = *(const f16x2_t*)(R3 + uo);
    f16x2_t v3 = *(const f16x2_t*)(C3 + vo);
    const float2 w2 = ((const float2*)W2)[lane];
    const f16x2_t w2h = {(_Float16)w2.x, (_Float16)w2.y};

    const f32x2_t zero2 = {0.f, 0.f};
    f32x2_t q0 = dot2_fp8x16(za0, zc0, zero2);
    f32x2_t q1 = dot2_fp8x16(za1, zc1, zero2);
    f32x2_t q2 = dot2_fp8x16(za2, zc2, zero2);
    f32x2_t q3 = dot2_fp8x16(za3, zc3, zero2);
    float p0 = q0.x + q0.y;
    float p1 = q1.x + q1.y;
    float p2 = q2.x + q2.y;
    float p3 = q3.x + q3.y;

    float t0 = head2(u0, v0, w2h);
    float t1 = head2(u1, v1, w2h);
    float t2 = head2(u2, v2, w2h);
    float t3 = head2(u3, v3, w2h);

    #pragma unroll
    for (int s = 1; s < 8; s <<= 1) {
        p0 += __shfl_xor(p0, s);
        p1 += __shfl_xor(p1, s);
        p2 += __shfl_xor(p2, s);
        p3 += __shfl_xor(p3, s);
        t0 += __shfl_xor(t0, s);
        t1 += __shfl_xor(t1, s);
        t2 += __shfl_xor(t2, s);
        t3 += __shfl_xor(t3, s);
    }

    if (lane == 0) {
        const float bb = b2[0];
        float w0 = softplus_f(t0 + bb);
        float w1 = softplus_f(t1 + bb);
        float ws = softplus_f(t2 + bb);
        float w3 = softplus_f(t3 + bb);
        if (full) {   // e0 % 4 == 0 and E % 4 == 0 -> 16 B aligned
            f32x4_t pv4 = {p0, p1, p2, p3};
            f32x4_t wv4 = {w0, w1, ws, w3};
            __builtin_nontemporal_store(pv4, (f32x4_t*)(out + e0));
            __builtin_nontemporal_store(wv4, (f32x4_t*)(out + E + e0));
        } else {
            const float pv[4] = {p0, p1, p2, p3};
            const float wv[4] = {w0, w1, ws, w3};
            for (int j = 0; j < 4 && e0 + j < E; ++j) {
                out[e0 + j]     = pv[j];
                out[E + e0 + j] = wv[j];
            }
        }
    }
}

#else  // !USE_FP8 — f16 records, 16 lanes per edge, 4 edges per group

__device__ __forceinline__ float dot_f16x8(uint4 a, uint4 c) {
    union { uint4 u; f16x2_t h[4]; } A, C;
    A.u = a; C.u = c;
    float p = 0.f;
#if __has_builtin(__builtin_amdgcn_fdot2)
    #pragma unroll
    for (int q = 0; q < 4; ++q)
        p = __builtin_amdgcn_fdot2(A.h[q], C.h[q], p, false);
#else
    #pragma unroll
    for (int q = 0; q < 4; ++q) {
        p = fmaf((float)A.h[q][0], (float)C.h[q][0], p);
        p = fmaf((float)A.h[q][1], (float)C.h[q][1], p);
    }
#endif
    return p;
}

__global__ __launch_bounds__(256) void edge_kernel_rec(
    const unsigned char* __restrict__ rec, const int* __restrict__ ei,
    const float* __restrict__ W2, const float* __restrict__ b2,
    float* __restrict__ out, int E)
{
    const int gid  = blockIdx.x * 256 + threadIdx.x;
    const int g    = gid >> 4;
    const int lane = threadIdx.x & 15;
    const int e0   = 4 * g;
    if (e0 >= E) return;
    const bool full = (e0 + 3) < E;

    int4 rr, cc;
    if (full) {
        rr = *(const int4*)(ei + e0);
        cc = *(const int4*)(ei + E + e0);
    } else {
        const int i1 = min(e0 + 1, E - 1), i2 = min(e0 + 2, E - 1), i3 = min(e0 + 3, E - 1);
        rr = make_int4(ei[e0], ei[i1], ei[i2], ei[i3]);
        cc = make_int4(ei[E + e0], ei[E + i1], ei[E + i2], ei[E + i3]);
    }

    const unsigned char* R0 = rec + (size_t)rr.x * RECB;
    const unsigned char* R1 = rec + (size_t)rr.y * RECB;
    const unsigned char* R2 = rec + (size_t)rr.z * RECB;
    const unsigned char* R3 = rec + (size_t)rr.w * RECB;
    const unsigned char* C0 = rec + (size_t)cc.x * RECB;
    const unsigned char* C1 = rec + (size_t)cc.y * RECB;
    const unsigned char* C2 = rec + (size_t)cc.z * RECB;
    const unsigned char* C3 = rec + (size_t)cc.w * RECB;

    const int zo = lane << 4;
    uint4 za0 = *(const uint4*)(R0 + zo);
    uint4 zc0 = *(const uint4*)(C0 + zo);
    uint4 za1 = *(const uint4*)(R1 + zo);
    uint4 zc1 = *(const uint4*)(C1 + zo);
    uint4 za2 = *(const uint4*)(R2 + zo);
    uint4 zc2 = *(const uint4*)(C2 + zo);
    uint4 za3 = *(const uint4*)(R3 + zo);
    uint4 zc3 = *(const uint4*)(C3 + zo);

    const int uo = UOFF + 2 * lane;
    const int vo = VOFF + 2 * lane;
    float u0 = (float)*(const _Float16*)(R0 + uo);
    float v0 = (float)*(const _Float16*)(C0 + vo);
    float u1 = (float)*(const _Float16*)(R1 + uo);
    float v1 = (float)*(const _Float16*)(C1 + vo);
    float u2 = (float)*(const _Float16*)(R2 + uo);
    float v2 = (float)*(const _Float16*)(C2 + vo);
    float u3 = (float)*(const _Float16*)(R3 + uo);
    float v3 = (float)*(const _Float16*)(C3 + vo);
    float w2 = W2[lane];

    float p0 = dot_f16x8(za0, zc0);
    float p1 = dot_f16x8(za1, zc1);
    float p2 = dot_f16x8(za2, zc2);
    float p3 = dot_f16x8(za3, zc3);
    #pragma unroll
    for (int s = 1; s < 16; s <<= 1) {
        p0 += __shfl_xor(p0, s);
        p1 += __shfl_xor(p1, s);
        p2 += __shfl_xor(p2, s);
        p3 += __shfl_xor(p3, s);
    }

    float t0 = fmaxf(u0 + v0, 0.f) * w2;
    float t1 = fmaxf(u1 + v1, 0.f) * w2;
    float t2 = fmaxf(u2 + v2, 0.f) * w2;
    float t3 = fmaxf(u3 + v3, 0.f) * w2;
    #pragma unroll
    for (int s = 1; s < 16; s <<= 1) {
        t0 += __shfl_xor(t0, s);
        t1 += __shfl_xor(t1, s);
        t2 += __shfl_xor(t2, s);
        t3 += __shfl_xor(t3, s);
    }

    if (lane == 0) {
        const float bb = b2[0];
        float w0 = softplus_f(t0 + bb);
        float w1 = softplus_f(t1 + bb);
        float ws = softplus_f(t2 + bb);
        float w3 = softplus_f(t3 + bb);
        if (full) {
            *(float4*)(out + e0)     = make_float4(p0, p1, p2, p3);
            *(float4*)(out + E + e0) = make_float4(w0, w1, ws, w3);
        } else {
            const float pv[4] = {p0, p1, p2, p3};
            const float wv[4] = {w0, w1, ws, w3};
            for (int j = 0; j < 4 && e0 + j < E; ++j) {
                out[e0 + j]     = pv[j];
                out[E + e0 + j] = wv[j];
            }
        }
    }
}
#endif  // USE_FP8

// ---------------------------------------------------------------------------
// Fallbacks (only if d_ws can't hold the record array)
// ---------------------------------------------------------------------------
__global__ __launch_bounds__(256) void precompute_scalar(
    const float* __restrict__ z, const float* __restrict__ W1,
    const float* __restrict__ b1,
    float* __restrict__ U, float* __restrict__ V, int n_nodes)
{
    const int node = blockIdx.x * 256 + threadIdx.x;
    if (node >= n_nodes) return;
    const float4* zp = (const float4*)(z + (size_t)node * NODE_D);
    float u[HID], v[HID];
    #pragma unroll
    for (int j = 0; j < HID; ++j) { u[j] = b1[j]; v[j] = 0.f; }
    #pragma unroll 1
    for (int c = 0; c < NODE_D / 4; ++c) {
        float4 za = zp[c];
        const float* wu = W1 + (size_t)c * 4 * HID;
        const float* wv = wu + NODE_D * HID;
        #pragma unroll
        for (int j = 0; j < HID; ++j) {
            u[j] = fmaf(za.x, wu[j], fmaf(za.y, wu[HID + j],
                   fmaf(za.z, wu[2 * HID + j], fmaf(za.w, wu[3 * HID + j], u[j]))));
            v[j] = fmaf(za.x, wv[j], fmaf(za.y, wv[HID + j],
                   fmaf(za.z, wv[2 * HID + j], fmaf(za.w, wv[3 * HID + j], v[j]))));
        }
    }
    float4* up = (float4*)(U + (size_t)node * HID);
    float4* vp = (float4*)(V + (size_t)node * HID);
    #pragma unroll
    for (int q = 0; q < 4; ++q) {
        up[q] = make_float4(u[4*q], u[4*q+1], u[4*q+2], u[4*q+3]);
        vp[q] = make_float4(v[4*q], v[4*q+1], v[4*q+2], v[4*q+3]);
    }
}

__global__ __launch_bounds__(256) void edge_kernel_f32(
    const float* __restrict__ z, const int* __restrict__ ei,
    const float* __restrict__ U, const float* __restrict__ V,
    const float* __restrict__ W2, const float* __restrict__ b2,
    float* __restrict__ out, int E)
{
    const int gid  = blockIdx.x * blockDim.x + threadIdx.x;
    const int eid  = gid >> 4;
    const int lane = threadIdx.x & 15;
    if (eid >= E) return;
    const int row = ei[eid];
    const int col = ei[E + eid];
    const float4* zr = (const float4*)(z + (size_t)row * NODE_D);
    const float4* zc = (const float4*)(z + (size_t)col * NODE_D);
    float4 a0 = zr[lane], a1 = zr[lane + 16];
    float4 c0 = zc[lane], c1 = zc[lane + 16];
    float p = a0.x*c0.x + a0.y*c0.y + a0.z*c0.z + a0.w*c0.w
            + a1.x*c1.x + a1.y*c1.y + a1.z*c1.z + a1.w*c1.w;
    p += __shfl_xor(p, 1); p += __shfl_xor(p, 2);
    p += __shfl_xor(p, 4); p += __shfl_xor(p, 8);
    float t = fmaxf(U[(size_t)row * HID + lane] + V[(size_t)col * HID + lane], 0.f) * W2[lane];
    t += __shfl_xor(t, 1); t += __shfl_xor(t, 2);
    t += __shfl_xor(t, 4); t += __shfl_xor(t, 8);
    if (lane == 0) {
        float x = t + b2[0];
        out[eid]     = p;
        out[E + eid] = softplus_f(x);
    }
}

extern "C" void kernel_launch(void* const* d_in, const int* in_sizes, int n_in,
                              void* d_out, int out_size, void* d_ws, size_t ws_size,
                              hipStream_t stream) {
    const float* z  = (const float*)d_in[0];
    const int*   ei = (const int*)  d_in[1];
    const float* W1 = (const float*)d_in[2];
    const float* b1 = (const float*)d_in[3];
    const float* W2 = (const float*)d_in[4];
    const float* b2 = (const float*)d_in[5];
    float* out = (float*)d_out;

    const int n_nodes = in_sizes[0] / NODE_D;   // 100000
    const int E       = in_sizes[1] / 2;        // 600000

    const size_t needRec = (size_t)n_nodes * RECB;   // 19.2 MB (fp8) / 32 MB (f16)
    const int use_rec    = (ws_size >= needRec);

    if (use_rec) {
        unsigned char* rec = (unsigned char*)d_ws;
        precompute_mfma<<<(n_nodes + 63) / 64, 256, 0, stream>>>(
            z, W1, b1, rec, n_nodes);
        const long long groups  = ((long long)E + 3) / 4;
#if USE_FP8
        const long long threads = groups * 8;
#else
        const long long threads = groups * 16;
#endif
        edge_kernel_rec<<<(unsigned)((threads + 255) / 256), 256, 0, stream>>>(
            rec, ei, W2, b2, out, E);
    } else {
        float* U = (float*)d_ws;
        float* V = U + (size_t)n_nodes * HID;
        precompute_scalar<<<(n_nodes + 255) / 256, 256, 0, stream>>>(
            z, W1, b1, U, V, n_nodes);
        const long long threads = (long long)E * 16;
        edge_kernel_f32<<<(unsigned)((threads + 255) / 256), 256, 0, stream>>>(
            z, ei, U, V, W2, b2, out, E);
    }
}

// Round 7
// 143.509 us; speedup vs baseline: 1.0332x; 1.0227x over previous
//
#include <hip/hip_runtime.h>
#include <math.h>

#define NODE_D 128
#define HID 16

#if __has_builtin(__builtin_amdgcn_cvt_pk_f32_fp8) && __has_builtin(__builtin_amdgcn_cvt_pk_fp8_f32)
#define USE_FP8 1
#define RECB 160   // [z fp8 128B][U fp8 16B][V fp8 16B] -> 2.5 cache lines
#define UOFF 128
#define VOFF 144
#else
#define USE_FP8 0
#define RECB 320   // [z f16 256B][U f16 32B][V f16 32B] -> 5 cache lines
#define UOFF 256
#define VOFF 288
#endif

typedef _Float16 f16x8_t __attribute__((ext_vector_type(8)));
typedef _Float16 f16x2_t __attribute__((ext_vector_type(2)));
typedef float    f32x4_t __attribute__((ext_vector_type(4)));
typedef float    f32x2_t __attribute__((ext_vector_type(2)));
typedef int      i32x4_t __attribute__((ext_vector_type(4)));

// ---------------------------------------------------------------------------
// Kernel 1 (MFMA f16): builds node records.
//   fp8 path: rec[n] = { z[n] fp8 x128 , U[n] fp8 x16 , V[n] fp8 x16 }  (160 B)
//   f16 path: rec[n] = { z[n] f16 x128 , U[n] f16 x16 , V[n] f16 x16 }  (320 B)
// W1 is [256][16] = 4096 floats, staged once per block into LDS in fragment
// order (i < 16 stages exactly 4096 — in-bounds).
// A layout: A[m=lane&15][k=quad*8+j (+32s)]; C/D: col=lane&15, row=quad*4+reg.
// ---------------------------------------------------------------------------
__global__ __launch_bounds__(256) void precompute_mfma(
    const float* __restrict__ z, const float* __restrict__ W1,
    const float* __restrict__ b1,
    unsigned char* __restrict__ rec, int n_nodes)
{
    __shared__ _Float16 ldsU[2048];   // 4 KB, fragment-ordered W1 rows 0..127
    __shared__ _Float16 ldsV[2048];   // 4 KB, rows 128..255

    const int tid = threadIdx.x;
    #pragma unroll
    for (int i = 0; i < 16; ++i) {
        const int e = i * 256 + tid;          // coalesced over W1's 4096 floats
        const float val = W1[e];
        int k = e >> 4;                        // W1 row (0..255)
        const int m = e & 15;                  // W1 col (hidden unit)
        _Float16* dst = ldsU;
        if (k >= NODE_D) { k -= NODE_D; dst = ldsV; }
        const int s = k >> 5, q = (k >> 3) & 3, jj = k & 7;
        dst[(((s * 4 + q) * 16 + m) << 3) + jj] = (_Float16)val;   // max 2047
    }
    __syncthreads();

    const int wave  = tid >> 6;
    const int lane  = tid & 63;
    const int m     = lane & 15;
    const int quad  = lane >> 4;
    const int nbase = blockIdx.x * 64 + wave * 16;
    const int node  = nbase + m;
    const int nodec = node < n_nodes ? node : (n_nodes - 1);

    // ---- A fragments from z (+ write compressed z into the record) ----
    // z is streamed once -> non-temporal loads (keep L2 for the record array).
    f16x8_t a[4];
    const f32x4_t* zrow = (const f32x4_t*)(z + (size_t)nodec * NODE_D);
    unsigned char* myrec = rec + (size_t)node * RECB;
    #pragma unroll
    for (int s = 0; s < 4; ++s) {
        f32x4_t f0 = __builtin_nontemporal_load(zrow + s * 8 + quad * 2);
        f32x4_t f1 = __builtin_nontemporal_load(zrow + s * 8 + quad * 2 + 1);
        union { f16x8_t v; _Float16 h[8]; uint4 q4; } ta;
        ta.h[0] = (_Float16)f0.x; ta.h[1] = (_Float16)f0.y;
        ta.h[2] = (_Float16)f0.z; ta.h[3] = (_Float16)f0.w;
        ta.h[4] = (_Float16)f1.x; ta.h[5] = (_Float16)f1.y;
        ta.h[6] = (_Float16)f1.z; ta.h[7] = (_Float16)f1.w;
        a[s] = ta.v;
        if (node < n_nodes) {
#if USE_FP8
            // pack 8 floats -> 8 fp8 e4m3 (RNE), dims s*32+quad*8 .. +7
            int w0 = __builtin_amdgcn_cvt_pk_fp8_f32(f0.x, f0.y, 0, false);
            w0     = __builtin_amdgcn_cvt_pk_fp8_f32(f0.z, f0.w, w0, true);
            int w1 = __builtin_amdgcn_cvt_pk_fp8_f32(f1.x, f1.y, 0, false);
            w1     = __builtin_amdgcn_cvt_pk_fp8_f32(f1.z, f1.w, w1, true);
            *(uint2*)(myrec + ((s * 4 + quad) << 3)) = make_uint2((unsigned)w0, (unsigned)w1);
#else
            *(uint4*)(myrec + ((s * 4 + quad) << 4)) = ta.q4;
#endif
        }
    }

    // ---- B fragments from LDS, MFMA (b1 folded into U accumulator) ----
    const float bias = b1[m];
    f32x4_t accU = {bias, bias, bias, bias};
    f32x4_t accV = {0.f, 0.f, 0.f, 0.f};
    #pragma unroll
    for (int s = 0; s < 4; ++s) {
        f16x8_t bu = *(const f16x8_t*)(ldsU + (((s * 4 + quad) * 16 + m) << 3));
        f16x8_t bv = *(const f16x8_t*)(ldsV + (((s * 4 + quad) * 16 + m) << 3));
        accU = __builtin_amdgcn_mfma_f32_16x16x32_f16(a[s], bu, accU, 0, 0, 0);
        accV = __builtin_amdgcn_mfma_f32_16x16x32_f16(a[s], bv, accV, 0, 0, 0);
    }

    // ---- store U/V into the record ----
    #pragma unroll
    for (int r = 0; r < 4; ++r) {
        const int nodeo = nbase + quad * 4 + r;
        if (nodeo < n_nodes) {
            unsigned char* orec = rec + (size_t)nodeo * RECB;
#if USE_FP8
            // fp8 e4m3 bytes; unit m of U at byte UOFF+m, of V at VOFF+m (max 159)
            int pu = __builtin_amdgcn_cvt_pk_fp8_f32(accU[r], accU[r], 0, false);
            int pv = __builtin_amdgcn_cvt_pk_fp8_f32(accV[r], accV[r], 0, false);
            orec[UOFF + m] = (unsigned char)(pu & 0xff);
            orec[VOFF + m] = (unsigned char)(pv & 0xff);
#else
            *(_Float16*)(orec + UOFF + 2 * m) = (_Float16)accU[r];
            *(_Float16*)(orec + VOFF + 2 * m) = (_Float16)accV[r];
#endif
        }
    }
}

__device__ __forceinline__ float softplus_f(float x) {
    return fmaxf(x, 0.f) + log1pf(expf(-fabsf(x)));
}

#if USE_FP8

// dot of 16 fp8 pairs (one uint4 each side), packed-f32 accumulation.
// 16 cvt_pk + 8 v_pk_fma_f32.
__device__ __forceinline__ f32x2_t dot2_fp8x16(uint4 a, uint4 c, f32x2_t acc) {
    const unsigned* au = (const unsigned*)&a;
    const unsigned* cu = (const unsigned*)&c;
    #pragma unroll
    for (int q = 0; q < 4; ++q) {
        f32x2_t alo = __builtin_amdgcn_cvt_pk_f32_fp8(au[q], false);
        f32x2_t clo = __builtin_amdgcn_cvt_pk_f32_fp8(cu[q], false);
        acc += alo * clo;                       // v_pk_fma_f32
        f32x2_t ahi = __builtin_amdgcn_cvt_pk_f32_fp8(au[q], true);
        f32x2_t chi = __builtin_amdgcn_cvt_pk_f32_fp8(cu[q], true);
        acc += ahi * chi;
    }
    return acc;
}

// relu(u+v) . w4  for 4 hidden units; su = 4 fp8 U-bytes, sv = 4 fp8 V-bytes.
// byte q of the dword = unit 4j+q, matching w4 = W2[4j..4j+3].
__device__ __forceinline__ float head4q(unsigned su, unsigned sv, f32x4_t w4) {
    f32x2_t ulo = __builtin_amdgcn_cvt_pk_f32_fp8(su, false);
    f32x2_t uhi = __builtin_amdgcn_cvt_pk_f32_fp8(su, true);
    f32x2_t vlo = __builtin_amdgcn_cvt_pk_f32_fp8(sv, false);
    f32x2_t vhi = __builtin_amdgcn_cvt_pk_f32_fp8(sv, true);
    f32x2_t hlo = ulo + vlo;
    f32x2_t hhi = uhi + vhi;
    hlo.x = fmaxf(hlo.x, 0.f); hlo.y = fmaxf(hlo.y, 0.f);
    hhi.x = fmaxf(hhi.x, 0.f); hhi.y = fmaxf(hhi.y, 0.f);
    return fmaf(hlo.x, w4.x, fmaf(hlo.y, w4.y, fmaf(hhi.x, w4.z, hhi.y * w4.w)));
}

// ---------------------------------------------------------------------------
// Kernel 2 (fp8 records, 160 B): 8 lanes per edge, 4 edges per group.
// All 8 lanes gather 16 B of z; lanes 0-3 additionally gather one U-dword of
// the row record + one V-dword of the col record (4 units each); lanes 4-7
// contribute 0 to the t-reduction. 3-stage reduction.
// ei loads and out stores are non-temporal (streamed once; keep L2 for rec).
// ---------------------------------------------------------------------------
__global__ __launch_bounds__(256) void edge_kernel_rec(
    const unsigned char* __restrict__ rec, const int* __restrict__ ei,
    const float* __restrict__ W2, const float* __restrict__ b2,
    float* __restrict__ out, int E)
{
    const int gid  = blockIdx.x * 256 + threadIdx.x;
    const int g    = gid >> 3;          // edge-quad id
    const int lane = threadIdx.x & 7;
    const int e0   = 4 * g;
    if (e0 >= E) return;
    const bool full = (e0 + 3) < E;

    i32x4_t rr, cc;
    if (full) {
        rr = __builtin_nontemporal_load((const i32x4_t*)(ei + e0));
        cc = __builtin_nontemporal_load((const i32x4_t*)(ei + E + e0));
    } else {
        const int i1 = min(e0 + 1, E - 1), i2 = min(e0 + 2, E - 1), i3 = min(e0 + 3, E - 1);
        rr = (i32x4_t){ei[e0], ei[i1], ei[i2], ei[i3]};
        cc = (i32x4_t){ei[E + e0], ei[E + i1], ei[E + i2], ei[E + i3]};
    }

    const unsigned char* R0 = rec + (size_t)rr.x * RECB;
    const unsigned char* R1 = rec + (size_t)rr.y * RECB;
    const unsigned char* R2 = rec + (size_t)rr.z * RECB;
    const unsigned char* R3 = rec + (size_t)rr.w * RECB;
    const unsigned char* C0 = rec + (size_t)cc.x * RECB;
    const unsigned char* C1 = rec + (size_t)cc.y * RECB;
    const unsigned char* C2 = rec + (size_t)cc.z * RECB;
    const unsigned char* C3 = rec + (size_t)cc.w * RECB;

    const int zo = lane << 4;     // 16 B per lane within the 128 B fp8 z block
    uint4 za0 = *(const uint4*)(R0 + zo);
    uint4 zc0 = *(const uint4*)(C0 + zo);
    uint4 za1 = *(const uint4*)(R1 + zo);
    uint4 zc1 = *(const uint4*)(C1 + zo);
    uint4 za2 = *(const uint4*)(R2 + zo);
    uint4 zc2 = *(const uint4*)(C2 + zo);
    uint4 za3 = *(const uint4*)(R3 + zo);
    uint4 zc3 = *(const uint4*)(C3 + zo);

    // lanes 0-3: U-dword (units 4l..4l+3) of row rec + V-dword of col rec
    float t0 = 0.f, t1 = 0.f, t2 = 0.f, t3 = 0.f;
    if (lane < 4) {
        const int uo = UOFF + (lane << 2);   // <= 140
        const int vo = VOFF + (lane << 2);   // <= 156
        unsigned su0 = *(const unsigned*)(R0 + uo);
        unsigned sv0 = *(const unsigned*)(C0 + vo);
        unsigned su1 = *(const unsigned*)(R1 + uo);
        unsigned sv1 = *(const unsigned*)(C1 + vo);
        unsigned su2 = *(const unsigned*)(R2 + uo);
        unsigned sv2 = *(const unsigned*)(C2 + vo);
        unsigned su3 = *(const unsigned*)(R3 + uo);
        unsigned sv3 = *(const unsigned*)(C3 + vo);
        const f32x4_t w4 = ((const f32x4_t*)W2)[lane];   // W2[4l..4l+3], l<4
        t0 = head4q(su0, sv0, w4);
        t1 = head4q(su1, sv1, w4);
        t2 = head4q(su2, sv2, w4);
        t3 = head4q(su3, sv3, w4);
    }

    const f32x2_t zero2 = {0.f, 0.f};
    f32x2_t q0 = dot2_fp8x16(za0, zc0, zero2);
    f32x2_t q1 = dot2_fp8x16(za1, zc1, zero2);
    f32x2_t q2 = dot2_fp8x16(za2, zc2, zero2);
    f32x2_t q3 = dot2_fp8x16(za3, zc3, zero2);
    float p0 = q0.x + q0.y;
    float p1 = q1.x + q1.y;
    float p2 = q2.x + q2.y;
    float p3 = q3.x + q3.y;

    #pragma unroll
    for (int s = 1; s < 8; s <<= 1) {
        p0 += __shfl_xor(p0, s);
        p1 += __shfl_xor(p1, s);
        p2 += __shfl_xor(p2, s);
        p3 += __shfl_xor(p3, s);
        t0 += __shfl_xor(t0, s);
        t1 += __shfl_xor(t1, s);
        t2 += __shfl_xor(t2, s);
        t3 += __shfl_xor(t3, s);
    }

    if (lane == 0) {
        const float bb = b2[0];
        float w0 = softplus_f(t0 + bb);
        float w1 = softplus_f(t1 + bb);
        float ws = softplus_f(t2 + bb);
        float w3 = softplus_f(t3 + bb);
        if (full) {   // e0 % 4 == 0 and E % 4 == 0 -> 16 B aligned
            f32x4_t pv4 = {p0, p1, p2, p3};
            f32x4_t wv4 = {w0, w1, ws, w3};
            __builtin_nontemporal_store(pv4, (f32x4_t*)(out + e0));
            __builtin_nontemporal_store(wv4, (f32x4_t*)(out + E + e0));
        } else {
            const float pv[4] = {p0, p1, p2, p3};
            const float wv[4] = {w0, w1, ws, w3};
            for (int j = 0; j < 4 && e0 + j < E; ++j) {
                out[e0 + j]     = pv[j];
                out[E + e0 + j] = wv[j];
            }
        }
    }
}

#else  // !USE_FP8 — f16 records, 16 lanes per edge, 4 edges per group

__device__ __forceinline__ float dot_f16x8(uint4 a, uint4 c) {
    union { uint4 u; f16x2_t h[4]; } A, C;
    A.u = a; C.u = c;
    float p = 0.f;
#if __has_builtin(__builtin_amdgcn_fdot2)
    #pragma unroll
    for (int q = 0; q < 4; ++q)
        p = __builtin_amdgcn_fdot2(A.h[q], C.h[q], p, false);
#else
    #pragma unroll
    for (int q = 0; q < 4; ++q) {
        p = fmaf((float)A.h[q][0], (float)C.h[q][0], p);
        p = fmaf((float)A.h[q][1], (float)C.h[q][1], p);
    }
#endif
    return p;
}

__global__ __launch_bounds__(256) void edge_kernel_rec(
    const unsigned char* __restrict__ rec, const int* __restrict__ ei,
    const float* __restrict__ W2, const float* __restrict__ b2,
    float* __restrict__ out, int E)
{
    const int gid  = blockIdx.x * 256 + threadIdx.x;
    const int g    = gid >> 4;
    const int lane = threadIdx.x & 15;
    const int e0   = 4 * g;
    if (e0 >= E) return;
    const bool full = (e0 + 3) < E;

    int4 rr, cc;
    if (full) {
        rr = *(const int4*)(ei + e0);
        cc = *(const int4*)(ei + E + e0);
    } else {
        const int i1 = min(e0 + 1, E - 1), i2 = min(e0 + 2, E - 1), i3 = min(e0 + 3, E - 1);
        rr = make_int4(ei[e0], ei[i1], ei[i2], ei[i3]);
        cc = make_int4(ei[E + e0], ei[E + i1], ei[E + i2], ei[E + i3]);
    }

    const unsigned char* R0 = rec + (size_t)rr.x * RECB;
    const unsigned char* R1 = rec + (size_t)rr.y * RECB;
    const unsigned char* R2 = rec + (size_t)rr.z * RECB;
    const unsigned char* R3 = rec + (size_t)rr.w * RECB;
    const unsigned char* C0 = rec + (size_t)cc.x * RECB;
    const unsigned char* C1 = rec + (size_t)cc.y * RECB;
    const unsigned char* C2 = rec + (size_t)cc.z * RECB;
    const unsigned char* C3 = rec + (size_t)cc.w * RECB;

    const int zo = lane << 4;
    uint4 za0 = *(const uint4*)(R0 + zo);
    uint4 zc0 = *(const uint4*)(C0 + zo);
    uint4 za1 = *(const uint4*)(R1 + zo);
    uint4 zc1 = *(const uint4*)(C1 + zo);
    uint4 za2 = *(const uint4*)(R2 + zo);
    uint4 zc2 = *(const uint4*)(C2 + zo);
    uint4 za3 = *(const uint4*)(R3 + zo);
    uint4 zc3 = *(const uint4*)(C3 + zo);

    const int uo = UOFF + 2 * lane;
    const int vo = VOFF + 2 * lane;
    float u0 = (float)*(const _Float16*)(R0 + uo);
    float v0 = (float)*(const _Float16*)(C0 + vo);
    float u1 = (float)*(const _Float16*)(R1 + uo);
    float v1 = (float)*(const _Float16*)(C1 + vo);
    float u2 = (float)*(const _Float16*)(R2 + uo);
    float v2 = (float)*(const _Float16*)(C2 + vo);
    float u3 = (float)*(const _Float16*)(R3 + uo);
    float v3 = (float)*(const _Float16*)(C3 + vo);
    float w2 = W2[lane];

    float p0 = dot_f16x8(za0, zc0);
    float p1 = dot_f16x8(za1, zc1);
    float p2 = dot_f16x8(za2, zc2);
    float p3 = dot_f16x8(za3, zc3);
    #pragma unroll
    for (int s = 1; s < 16; s <<= 1) {
        p0 += __shfl_xor(p0, s);
        p1 += __shfl_xor(p1, s);
        p2 += __shfl_xor(p2, s);
        p3 += __shfl_xor(p3, s);
    }

    float t0 = fmaxf(u0 + v0, 0.f) * w2;
    float t1 = fmaxf(u1 + v1, 0.f) * w2;
    float t2 = fmaxf(u2 + v2, 0.f) * w2;
    float t3 = fmaxf(u3 + v3, 0.f) * w2;
    #pragma unroll
    for (int s = 1; s < 16; s <<= 1) {
        t0 += __shfl_xor(t0, s);
        t1 += __shfl_xor(t1, s);
        t2 += __shfl_xor(t2, s);
        t3 += __shfl_xor(t3, s);
    }

    if (lane == 0) {
        const float bb = b2[0];
        float w0 = softplus_f(t0 + bb);
        float w1 = softplus_f(t1 + bb);
        float ws = softplus_f(t2 + bb);
        float w3 = softplus_f(t3 + bb);
        if (full) {
            *(float4*)(out + e0)     = make_float4(p0, p1, p2, p3);
            *(float4*)(out + E + e0) = make_float4(w0, w1, ws, w3);
        } else {
            const float pv[4] = {p0, p1, p2, p3};
            const float wv[4] = {w0, w1, ws, w3};
            for (int j = 0; j < 4 && e0 + j < E; ++j) {
                out[e0 + j]     = pv[j];
                out[E + e0 + j] = wv[j];
            }
        }
    }
}
#endif  // USE_FP8

// ---------------------------------------------------------------------------
// Fallbacks (only if d_ws can't hold the record array)
// ---------------------------------------------------------------------------
__global__ __launch_bounds__(256) void precompute_scalar(
    const float* __restrict__ z, const float* __restrict__ W1,
    const float* __restrict__ b1,
    float* __restrict__ U, float* __restrict__ V, int n_nodes)
{
    const int node = blockIdx.x * 256 + threadIdx.x;
    if (node >= n_nodes) return;
    const float4* zp = (const float4*)(z + (size_t)node * NODE_D);
    float u[HID], v[HID];
    #pragma unroll
    for (int j = 0; j < HID; ++j) { u[j] = b1[j]; v[j] = 0.f; }
    #pragma unroll 1
    for (int c = 0; c < NODE_D / 4; ++c) {
        float4 za = zp[c];
        const float* wu = W1 + (size_t)c * 4 * HID;
        const float* wv = wu + NODE_D * HID;
        #pragma unroll
        for (int j = 0; j < HID; ++j) {
            u[j] = fmaf(za.x, wu[j], fmaf(za.y, wu[HID + j],
                   fmaf(za.z, wu[2 * HID + j], fmaf(za.w, wu[3 * HID + j], u[j]))));
            v[j] = fmaf(za.x, wv[j], fmaf(za.y, wv[HID + j],
                   fmaf(za.z, wv[2 * HID + j], fmaf(za.w, wv[3 * HID + j], v[j]))));
        }
    }
    float4* up = (float4*)(U + (size_t)node * HID);
    float4* vp = (float4*)(V + (size_t)node * HID);
    #pragma unroll
    for (int q = 0; q < 4; ++q) {
        up[q] = make_float4(u[4*q], u[4*q+1], u[4*q+2], u[4*q+3]);
        vp[q] = make_float4(v[4*q], v[4*q+1], v[4*q+2], v[4*q+3]);
    }
}

__global__ __launch_bounds__(256) void edge_kernel_f32(
    const float* __restrict__ z, const int* __restrict__ ei,
    const float* __restrict__ U, const float* __restrict__ V,
    const float* __restrict__ W2, const float* __restrict__ b2,
    float* __restrict__ out, int E)
{
    const int gid  = blockIdx.x * blockDim.x + threadIdx.x;
    const int eid  = gid >> 4;
    const int lane = threadIdx.x & 15;
    if (eid >= E) return;
    const int row = ei[eid];
    const int col = ei[E + eid];
    const float4* zr = (const float4*)(z + (size_t)row * NODE_D);
    const float4* zc = (const float4*)(z + (size_t)col * NODE_D);
    float4 a0 = zr[lane], a1 = zr[lane + 16];
    float4 c0 = zc[lane], c1 = zc[lane + 16];
    float p = a0.x*c0.x + a0.y*c0.y + a0.z*c0.z + a0.w*c0.w
            + a1.x*c1.x + a1.y*c1.y + a1.z*c1.z + a1.w*c1.w;
    p += __shfl_xor(p, 1); p += __shfl_xor(p, 2);
    p += __shfl_xor(p, 4); p += __shfl_xor(p, 8);
    float t = fmaxf(U[(size_t)row * HID + lane] + V[(size_t)col * HID + lane], 0.f) * W2[lane];
    t += __shfl_xor(t, 1); t += __shfl_xor(t, 2);
    t += __shfl_xor(t, 4); t += __shfl_xor(t, 8);
    if (lane == 0) {
        float x = t + b2[0];
        out[eid]     = p;
        out[E + eid] = softplus_f(x);
    }
}

extern "C" void kernel_launch(void* const* d_in, const int* in_sizes, int n_in,
                              void* d_out, int out_size, void* d_ws, size_t ws_size,
                              hipStream_t stream) {
    const float* z  = (const float*)d_in[0];
    const int*   ei = (const int*)  d_in[1];
    const float* W1 = (const float*)d_in[2];
    const float* b1 = (const float*)d_in[3];
    const float* W2 = (const float*)d_in[4];
    const float* b2 = (const float*)d_in[5];
    float* out = (float*)d_out;

    const int n_nodes = in_sizes[0] / NODE_D;   // 100000
    const int E       = in_sizes[1] / 2;        // 600000

    const size_t needRec = (size_t)n_nodes * RECB;   // 16 MB (fp8) / 32 MB (f16)
    const int use_rec    = (ws_size >= needRec);

    if (use_rec) {
        unsigned char* rec = (unsigned char*)d_ws;
        precompute_mfma<<<(n_nodes + 63) / 64, 256, 0, stream>>>(
            z, W1, b1, rec, n_nodes);
        const long long groups  = ((long long)E + 3) / 4;
#if USE_FP8
        const long long threads = groups * 8;
#else
        const long long threads = groups * 16;
#endif
        edge_kernel_rec<<<(unsigned)((threads + 255) / 256), 256, 0, stream>>>(
            rec, ei, W2, b2, out, E);
    } else {
        float* U = (float*)d_ws;
        float* V = U + (size_t)n_nodes * HID;
        precompute_scalar<<<(n_nodes + 255) / 256, 256, 0, stream>>>(
            z, W1, b1, U, V, n_nodes);
        const long long threads = (long long)E * 16;
        edge_kernel_f32<<<(unsigned)((threads + 255) / 256), 256, 0, stream>>>(
            z, ei, U, V, W2, b2, out, E);
    }
}